// Round 13
// baseline (889.362 us; speedup 1.0000x reference)
//
#include <hip/hip_runtime.h>

// QuantizedLinear M=8192 K=4096 N=11008.
// r13: r9 (tiled workspace, lane-linear LDS, 0 conflicts, A3+B2 rings, vmcnt(6)) with
// m201-style C-QUADRANT SNAKE phases: ph0 reads A-mh0+B-n0 (12, lgkmcnt(8) paced);
// ph1 reads B-n1 (4); ph2 reads A-mh1 (8); ph3 reads ZERO. B-frags persist whole tile.
// Each phase: [reads][1 half-tile stage][barrier][lgkmcnt(0)][8x mfma_32x32x16 full-K][barrier].
// Stage plan per tile t: ph0->Bhi[t+1](pn), ph1->Alo[t+2](free parity), ph2->Ahi[t+2],
// ph3->Blo[t+2](p, after last B read at ph1). vmcnt(6) at ph3 confirms tile t+1.

#define K_DIM 4096
#define N_DIM 11008
#define M_DIM 8192
#define NT_K 64       // K_DIM / 64
#define AB_OFF 98304  // A region: 3 parities x 32KB; B region: 2 parities x 32KB
#define TILE_BYTES 2097152  // per 256-row stripe: 64 ktiles * 32KB

typedef _Float16 f16;
typedef _Float16 f16x8 __attribute__((ext_vector_type(8)));
typedef float f32x16 __attribute__((ext_vector_type(16)));
typedef float fv4 __attribute__((ext_vector_type(4)));
typedef int iv4 __attribute__((ext_vector_type(4)));

__device__ __forceinline__ void gload16(const void* g, void* lds) {
  __builtin_amdgcn_global_load_lds(
      (__attribute__((address_space(1))) void*)g,
      (__attribute__((address_space(3))) void*)lds,
      16, 0, 0);
}

// fused prepass into tiled layout (r9, passed).
// flat 16B-position i: [5:0]=lane, [9:6]=F, [10]=kk, [16:11]=t, [..:17]=stripe.
// row = stripe*256 + (F>>1)*32 + (lane&31); k = t*64 + kk*32 + (F&1)*16 + (lane>>5)*8.
__global__ __launch_bounds__(256) void prep_kernel(const float* __restrict__ x,
                                                   f16* __restrict__ xo, int n16x,
                                                   const int* __restrict__ q,
                                                   const float* __restrict__ amax,
                                                   f16* __restrict__ wo, int n16w) {
  int i = blockIdx.x * blockDim.x + threadIdx.x;
  if (i < n16x) {
    const int lam = i & 63;
    const int F = (i >> 6) & 15;
    const int kk = (i >> 10) & 1;
    const int t = (i >> 11) & 63;
    const int mt = i >> 17;
    const int row = mt * 256 + ((F >> 1) << 5) + (lam & 31);
    const int kc = t * 64 + (kk << 5) + ((F & 1) << 4) + ((lam >> 5) << 3);
    const fv4* src = (const fv4*)(x + (size_t)row * K_DIM + kc);
    fv4 a = __builtin_nontemporal_load(src);
    fv4 b = __builtin_nontemporal_load(src + 1);
    f16x8 o;
    o[0] = (f16)a.x; o[1] = (f16)a.y; o[2] = (f16)a.z; o[3] = (f16)a.w;
    o[4] = (f16)b.x; o[5] = (f16)b.y; o[6] = (f16)b.z; o[7] = (f16)b.w;
    *(f16x8*)(xo + (size_t)i * 8) = o;
  } else {
    int j = i - n16x;
    if (j >= n16w) return;
    const int lam = j & 63;
    const int F = (j >> 6) & 15;
    const int kk = (j >> 10) & 1;
    const int t = (j >> 11) & 63;
    const int nt = j >> 17;
    const int row = nt * 256 + ((F >> 1) << 5) + (lam & 31);
    const int kc = t * 64 + (kk << 5) + ((F & 1) << 4) + ((lam >> 5) << 3);
    const size_t base = (size_t)row * K_DIM + kc;
    const iv4* src = (const iv4*)(q + base);
    iv4 a = __builtin_nontemporal_load(src);
    iv4 b = __builtin_nontemporal_load(src + 1);
    float s = amax[base >> 6] * (1.0f / 7.0f);
    f16x8 o;
    o[0] = (f16)((float)a.x * s); o[1] = (f16)((float)a.y * s);
    o[2] = (f16)((float)a.z * s); o[3] = (f16)((float)a.w * s);
    o[4] = (f16)((float)b.x * s); o[5] = (f16)((float)b.y * s);
    o[6] = (f16)((float)b.z * s); o[7] = (f16)((float)b.w * s);
    *(f16x8*)(wo + (size_t)j * 8) = o;
  }
}

// LDS: A(parity ap in {0,32768,65536}, kk) @ ap + kk*16384; B(parity p, kk) @ AB_OFF+p*32768+kk*16384.
// Chunk (rowblk, ks16) @ +(rowblk*2+ks16)*1024, lane-linear (l*16).
__global__ __launch_bounds__(512, 2) void gemm_f16_bt(const f16* __restrict__ A,
                                                      const f16* __restrict__ B,
                                                      const float* __restrict__ bias,
                                                      float* __restrict__ C) {
  __shared__ __align__(16) char lds[163840];

  const int tid = threadIdx.x;
  const int w = tid >> 6;
  const int l = tid & 63;
  const int wr = w >> 2;  // 0..1 : 128 M-rows each
  const int wc = w & 3;   // 0..3 : 64 N-cols each

  // bijective XCD swizzle: nwg = 1376 = 8 * 172
  const int wg = blockIdx.x;
  const int swz = (wg & 7) * 172 + (wg >> 3);
  const int mt = swz / 43;
  const int nt = swz % 43;
  const int m0 = mt * 256;
  const int n0 = nt * 256;

  const char* Abase = (const char*)A + (size_t)mt * TILE_BYTES + (w << 10) + (l << 4);
  const char* Bbase = (const char*)B + (size_t)nt * TILE_BYTES + (w << 10) + (l << 4);
  char* ldsc = (char*)lds;
  const int l16 = l << 4;

#define STAGE_A(dst_off, koff)                 \
  {                                            \
    char* d_ = ldsc + (dst_off) + (w << 10);   \
    gload16(Abase + (koff), d_);               \
    gload16(Abase + (koff) + 8192, d_ + 8192); \
  }
#define STAGE_B(dst_off, koff)                 \
  {                                            \
    char* d_ = ldsc + (dst_off) + (w << 10);   \
    gload16(Bbase + (koff), d_);               \
    gload16(Bbase + (koff) + 8192, d_ + 8192); \
  }
  // A chunk (mf in wave, ks in 0..3): rowblk = wr*4+mf; addr = ap + (ks>>1)*16384
  //   + ((rowblk*2)|(ks&1))*1024 + l*16.  a8[m*4+ks] holds quadrant pair m in {0,1}.
#define READ_A(mh)                                                            \
  {                                                                           \
    _Pragma("unroll") for (int m = 0; m < 2; ++m)                             \
    _Pragma("unroll") for (int ks = 0; ks < 4; ++ks) {                        \
      const int rowblk = (wr << 2) + ((mh) << 1) + m;                         \
      a8[m * 4 + ks] = *(const f16x8*)(ldsc + ap + ((ks >> 1) << 14) +        \
                                       (((rowblk << 1) | (ks & 1)) << 10) + l16); \
    }                                                                         \
  }
#define READ_B(nf)                                                            \
  {                                                                           \
    const int colblk = (wc << 1) + (nf);                                      \
    _Pragma("unroll") for (int ks = 0; ks < 4; ++ks)                          \
      b8[(nf)][ks] = *(const f16x8*)(ldsc + Bb + ((ks >> 1) << 14) +          \
                                     (((colblk << 1) | (ks & 1)) << 10) + l16); \
  }
#define MFMA_Q(mh, nf)                                                        \
  {                                                                           \
    __builtin_amdgcn_s_setprio(1);                                            \
    _Pragma("unroll") for (int ks = 0; ks < 4; ++ks)                          \
    _Pragma("unroll") for (int m = 0; m < 2; ++m)                             \
      acc[(mh) * 2 + m][(nf)] = __builtin_amdgcn_mfma_f32_32x32x16_f16(       \
          a8[m * 4 + ks], b8[(nf)][ks], acc[(mh) * 2 + m][(nf)], 0, 0, 0);    \
    __builtin_amdgcn_s_setprio(0);                                            \
  }

  f32x16 acc[4][2];
#pragma unroll
  for (int i = 0; i < 4; ++i)
#pragma unroll
    for (int j = 0; j < 2; ++j) acc[i][j] = (f32x16)0.f;

  // prologue: Alo0,Ahi0,Blo0,Bhi0,Alo1,Ahi1,Blo1 = 14 gloads; vmcnt(6) confirms tile 0
  STAGE_A(0, 0);
  STAGE_A(16384, 16384);
  STAGE_B(AB_OFF, 0);
  STAGE_B(AB_OFF + 16384, 16384);
  STAGE_A(32768, 32768);
  STAGE_A(32768 + 16384, 32768 + 16384);
  STAGE_B(AB_OFF + 32768, 32768);
  asm volatile("s_waitcnt vmcnt(6)" ::: "memory");
  __builtin_amdgcn_s_barrier();

  int ap = 0;       // A parity base of tile t
  int ap2 = 65536;  // A parity base of tile t+2

  f16x8 a8[8];
  f16x8 b8[2][4];

  for (int t = 0; t < NT_K; ++t) {
    const int p = t & 1;
    const int pn = p ^ 1;
    const int Bb = AB_OFF + p * 32768;
    const int Bn = AB_OFF + pn * 32768;
    const int t1 = (t + 1 < NT_K) ? (t + 1) : (NT_K - 1);
    const int t2 = (t + 2 < NT_K) ? (t + 2) : (NT_K - 1);
    const int k1 = t1 * 32768;
    const int k2 = t2 * 32768;

    // ph0: quadrant (mh0, nf0); reads A-mh0 (8) + B-n0 (4); stage Bhi[t+1]
    READ_A(0);
    READ_B(0);
    STAGE_B(Bn + 16384, k1 + 16384);
    asm volatile("s_waitcnt lgkmcnt(8)" ::: "memory");  // pace the 12-read phase
    __builtin_amdgcn_s_barrier();
    asm volatile("s_waitcnt lgkmcnt(0)" ::: "memory");
    __builtin_amdgcn_sched_barrier(0);
    MFMA_Q(0, 0);
    __builtin_amdgcn_s_barrier();

    // ph1: quadrant (mh0, nf1); reads B-n1 (4); stage Alo[t+2]
    READ_B(1);
    STAGE_A(ap2, k2);
    __builtin_amdgcn_s_barrier();
    asm volatile("s_waitcnt lgkmcnt(0)" ::: "memory");
    __builtin_amdgcn_sched_barrier(0);
    MFMA_Q(0, 1);
    __builtin_amdgcn_s_barrier();

    // ph2: quadrant (mh1, nf1); reads A-mh1 (8, reuses a8); stage Ahi[t+2]
    READ_A(1);
    STAGE_A(ap2 + 16384, k2 + 16384);
    __builtin_amdgcn_s_barrier();
    asm volatile("s_waitcnt lgkmcnt(0)" ::: "memory");
    __builtin_amdgcn_sched_barrier(0);
    MFMA_Q(1, 1);
    __builtin_amdgcn_s_barrier();

    // ph3: quadrant (mh1, nf0); ZERO reads; stage Blo[t+2]
    STAGE_B(Bb, k2);
    __builtin_amdgcn_s_barrier();
    MFMA_Q(1, 0);
    asm volatile("s_waitcnt vmcnt(6)" ::: "memory");  // confirms tile t+1 fully in LDS
    __builtin_amdgcn_s_barrier();

    ap += 32768;  if (ap == AB_OFF) ap = 0;
    ap2 += 32768; if (ap2 == AB_OFF) ap2 = 0;
  }

  // epilogue: 32x32 C/D layout col = lane&31, row = (reg&3) + 8*(reg>>2) + 4*(lane>>5)
  const int l31 = l & 31;
  const int rbase = 4 * (l >> 5);
  float bv[2];
#pragma unroll
  for (int nf = 0; nf < 2; ++nf) bv[nf] = bias[n0 + wc * 64 + nf * 32 + l31];
#pragma unroll
  for (int mf = 0; mf < 4; ++mf) {
#pragma unroll
    for (int nf = 0; nf < 2; ++nf) {
      const size_t col = n0 + wc * 64 + nf * 32 + l31;
#pragma unroll
      for (int qd = 0; qd < 4; ++qd) {
#pragma unroll
        for (int j = 0; j < 4; ++j) {
          const int row = m0 + wr * 128 + mf * 32 + rbase + 8 * qd + j;
          __builtin_nontemporal_store(acc[mf][nf][qd * 4 + j] + bv[nf],
                                      &C[(size_t)row * N_DIM + col]);
        }
      }
    }
  }
#undef STAGE_A
#undef STAGE_B
#undef READ_A
#undef READ_B
#undef MFMA_Q
}

extern "C" void kernel_launch(void* const* d_in, const int* in_sizes, int n_in,
                              void* d_out, int out_size, void* d_ws, size_t ws_size,
                              hipStream_t stream) {
  const float* x = (const float*)d_in[0];
  const int* wq = (const int*)d_in[1];
  const float* amax = (const float*)d_in[2];
  const float* bias = (const float*)d_in[3];
  float* out = (float*)d_out;

  f16* Xh = (f16*)d_ws;                                       // 64 MB, tiled
  f16* Wh = (f16*)((char*)d_ws + (size_t)M_DIM * K_DIM * 2);  // 90.25 MB, tiled

  {
    int n16x = M_DIM * K_DIM / 8;  // 4,194,304
    int n16w = N_DIM * K_DIM / 8;  // 5,636,096
    int nthr = n16x + n16w;
    prep_kernel<<<(nthr + 255) / 256, 256, 0, stream>>>(x, Xh, n16x, wq, amax, Wh, n16w);
  }
  {
    dim3 grid((M_DIM / 256) * (N_DIM / 256));  // 32*43 = 1376
    gemm_f16_bt<<<grid, 512, 0, stream>>>(Xh, Wh, bias, out);
  }
}